// Round 1
// baseline (1941.883 us; speedup 1.0000x reference)
//
#include <hip/hip_runtime.h>
#include <cmath>
#include <math.h>

namespace {

constexpr int Bn = 4;
constexpr int Cn = 64;
constexpr int Wn = 64;
constexpr int Hn = 1024;
constexpr int HWn = Wn * Hn;      // 65536
constexpr int CHWn = Cn * HWn;    // 4194304

struct ShiftConsts { float m[27]; };  // m0[9] | m1[9] | m2[9]

// ---------------- GroupNorm stats: one block per (b, g) ----------------
__global__ __launch_bounds__(256) void gn_stats_kernel(
    const float* __restrict__ x, float* __restrict__ stats) {
  const int bg = blockIdx.x;
  const int b = bg >> 5, g = bg & 31;
  // channels 2g, 2g+1 are contiguous in memory: one flat 2*HW range
  const float* base = x + (size_t)b * CHWn + (size_t)(2 * g) * HWn;
  float s = 0.f, s2 = 0.f;
  for (int e = threadIdx.x; e < 2 * HWn; e += 256) {
    const float v = base[e];
    s += v; s2 += v * v;
  }
  #pragma unroll
  for (int off = 32; off > 0; off >>= 1) {
    s  += __shfl_down(s, off, 64);
    s2 += __shfl_down(s2, off, 64);
  }
  __shared__ float red[8];
  const int wid = threadIdx.x >> 6, lid = threadIdx.x & 63;
  if (lid == 0) { red[wid * 2] = s; red[wid * 2 + 1] = s2; }
  __syncthreads();
  if (threadIdx.x == 0) {
    float ts = 0.f, t2 = 0.f;
    #pragma unroll
    for (int i = 0; i < 4; i++) { ts += red[i * 2]; t2 += red[i * 2 + 1]; }
    const float inv = 1.0f / (2.0f * HWn);
    const float mean = ts * inv;
    const float var = t2 * inv - mean * mean;
    stats[bg * 2] = mean;
    stats[bg * 2 + 1] = rsqrtf(var + 1e-6f);
  }
}

// ------- Dual GEMM: Y = W_a @ relu(gn(x)),  Z = W_b @ relu(gn(x)) + b1 -------
// w1 layout [64][131]: cols 0..63 -> W_a (shifted operand), 64..127 -> W_b, 128..130 -> pe.
// Block = 64 h-points x all 64 out-channels; thread = 4x4 tile.
__global__ __launch_bounds__(256, 3) void dual_gemm_kernel(
    const float* __restrict__ x, const float* __restrict__ stats,
    const float* __restrict__ gw, const float* __restrict__ gb,
    const float* __restrict__ w1, const float* __restrict__ b1,
    float* __restrict__ Y, float* __restrict__ Z) {
  __shared__ __align__(16) float wa[64 * 68];  // [k][o], pad 68
  __shared__ __align__(16) float wb[64 * 68];
  __shared__ __align__(16) float xs[64 * 68];  // [c(=k)][j]
  const int blk = blockIdx.x;
  const int h0 = (blk & 15) * 64;
  const int w  = (blk >> 4) & 63;
  const int b  = blk >> 10;
  const int t  = threadIdx.x;
  {
    const int k = t & 63, o0 = t >> 6;
    #pragma unroll
    for (int i = 0; i < 16; i++) {
      const int o = o0 + i * 4;
      wa[k * 68 + o] = w1[o * 131 + k];
      wb[k * 68 + o] = w1[o * 131 + 64 + k];
    }
  }
  {
    const int j = t & 63;
    const int c0 = (t >> 6) * 16;
    #pragma unroll
    for (int i = 0; i < 16; i++) {
      const int c = c0 + i;
      const int sidx = (b * 32 + (c >> 1)) * 2;
      const float mean = stats[sidx], rstd = stats[sidx + 1];
      float v = x[(size_t)b * CHWn + (size_t)c * HWn + w * Hn + h0 + j];
      v = (v - mean) * rstd * gw[c] + gb[c];
      xs[c * 68 + j] = fmaxf(v, 0.f);
    }
  }
  __syncthreads();
  const int tx = t & 15, ty = t >> 4;
  const int j4 = tx * 4, o4 = ty * 4;
  float accY[4][4] = {{0.f}};
  float accZ[4][4] = {{0.f}};
  for (int k = 0; k < 64; k++) {
    const float4 a4 = *(const float4*)&wa[k * 68 + o4];
    const float4 z4 = *(const float4*)&wb[k * 68 + o4];
    const float4 x4 = *(const float4*)&xs[k * 68 + j4];
    const float av[4] = {a4.x, a4.y, a4.z, a4.w};
    const float zv[4] = {z4.x, z4.y, z4.z, z4.w};
    const float xv[4] = {x4.x, x4.y, x4.z, x4.w};
    #pragma unroll
    for (int io = 0; io < 4; io++)
      #pragma unroll
      for (int ij = 0; ij < 4; ij++) {
        accY[io][ij] += av[io] * xv[ij];
        accZ[io][ij] += zv[io] * xv[ij];
      }
  }
  #pragma unroll
  for (int io = 0; io < 4; io++) {
    const int o = o4 + io;
    const float bias = b1[o];
    const size_t idx = (size_t)b * CHWn + (size_t)o * HWn + w * Hn + h0 + j4;
    const float4 vy = make_float4(accY[io][0], accY[io][1], accY[io][2], accY[io][3]);
    const float4 vz = make_float4(accZ[io][0] + bias, accZ[io][1] + bias,
                                  accZ[io][2] + bias, accZ[io][3] + bias);
    *(float4*)&Y[idx] = vy;
    *(float4*)&Z[idx] = vz;
  }
}

// ---- 9-shift fused: out = max_s( W2 @ relu(Y_s + Z + pe_s) ) + b2 (+ x) ----
// Block = 128 h-points x 64 out-channels; thread = 8x4 tile.
__global__ __launch_bounds__(256, 3) void shift_max_kernel(
    const float* __restrict__ Y, const float* __restrict__ Z,
    const float* __restrict__ r, const float* __restrict__ w1,
    const float* __restrict__ w2, const float* __restrict__ b2,
    const float* __restrict__ xres, const int add_res,
    float* __restrict__ out, const ShiftConsts sc) {
  __shared__ __align__(16) float w2s[64 * 68];   // [k][oo], pad 68
  __shared__ __align__(16) float h1s[64 * 128];  // [k][j], no pad needed (k uniform per wave)
  __shared__ float rsh[3][132];                  // [w-1..w+1][h0-1..h0+128]
  __shared__ float pw0[64], pw1[64], pw2[64], b2s[64];
  __shared__ float sm[27];
  const int blk = blockIdx.x;
  const int h0 = (blk & 7) * 128;
  const int w  = (blk >> 3) & 63;
  const int b  = blk >> 9;
  const int t  = threadIdx.x;
  {
    const int k = t & 63, o0 = t >> 6;
    #pragma unroll
    for (int i = 0; i < 16; i++) {
      const int o = o0 + i * 4;
      w2s[k * 68 + o] = w2[o * 64 + k];
    }
  }
  if (t < 64) {
    pw0[t] = w1[t * 131 + 128];
    pw1[t] = w1[t * 131 + 129];
    pw2[t] = w1[t * 131 + 130];
    b2s[t] = b2[t];
  }
  if (t < 27) sm[t] = sc.m[t];
  for (int i = t; i < 3 * 130; i += 256) {
    const int wi = i / 130, jj = i - wi * 130;
    const int wsrc = (w + wi - 1 + 64) & 63;
    const int hsrc = (h0 + jj - 1 + 1024) & 1023;
    rsh[wi][jj] = r[(size_t)b * HWn + wsrc * Hn + hsrc];
  }
  __syncthreads();

  // phase-a mapping: thread -> (j = t&127, k-range of 32)
  const int aj = t & 127;
  const int ak0 = (t >> 7) * 32;
  const float rc = rsh[1][aj + 1];

  // phase-b mapping: 8 oo x 4 j per thread
  const int tx = t & 31, ty = t >> 5;
  const int j4 = tx * 4, o8 = ty * 8;
  float omax[8][4];
  #pragma unroll
  for (int io = 0; io < 8; io++)
    #pragma unroll
    for (int ij = 0; ij < 4; ij++) omax[io][ij] = -INFINITY;

  for (int s = 0; s < 9; s++) {
    const int sw = s / 3 - 1, sh = s % 3 - 1;
    const float m0 = sm[s], m1 = sm[9 + s], m2 = sm[18 + s];
    const int wsrc = (w - sw + 64) & 63;
    const int hsrc = (h0 + aj - sh + 1024) & 1023;
    const float rsv = rsh[1 - sw][aj - sh + 1];
    const float* Yb = Y + (size_t)b * CHWn + (size_t)wsrc * Hn;
    const float* Zb = Z + (size_t)b * CHWn + (size_t)w * Hn;
    __syncthreads();  // previous GEMM's h1s readers done
    for (int i = 0; i < 32; i++) {
      const int k = ak0 + i;
      const float yv = Yb[(size_t)k * HWn + hsrc];
      const float zv = Zb[(size_t)k * HWn + h0 + aj];
      const float vs = m0 * pw0[k] + m1 * pw1[k] + m2 * pw2[k];
      const float h1 = yv + zv + rsv * vs - rc * pw0[k];
      h1s[k * 128 + aj] = fmaxf(h1, 0.f);
    }
    __syncthreads();
    float cur[8][4] = {{0.f}};
    for (int k = 0; k < 64; k++) {
      const float4 a0 = *(const float4*)&w2s[k * 68 + o8];
      const float4 a1 = *(const float4*)&w2s[k * 68 + o8 + 4];
      const float4 bv = *(const float4*)&h1s[k * 128 + j4];
      const float av[8] = {a0.x, a0.y, a0.z, a0.w, a1.x, a1.y, a1.z, a1.w};
      const float bw[4] = {bv.x, bv.y, bv.z, bv.w};
      #pragma unroll
      for (int io = 0; io < 8; io++)
        #pragma unroll
        for (int ij = 0; ij < 4; ij++)
          cur[io][ij] += av[io] * bw[ij];
    }
    #pragma unroll
    for (int io = 0; io < 8; io++)
      #pragma unroll
      for (int ij = 0; ij < 4; ij++)
        omax[io][ij] = fmaxf(omax[io][ij], cur[io][ij]);
  }

  #pragma unroll
  for (int io = 0; io < 8; io++) {
    const int o = o8 + io;
    const float bias = b2s[o];
    const size_t idx = (size_t)b * CHWn + (size_t)o * HWn + w * Hn + h0 + j4;
    float4 v = make_float4(omax[io][0] + bias, omax[io][1] + bias,
                           omax[io][2] + bias, omax[io][3] + bias);
    if (add_res) {
      v.x += xres[idx];
      v.y += xres[idx + 1];
      v.z += xres[idx + 2];
      v.w += xres[idx + 3];
    }
    *(float4*)&out[idx] = v;
  }
}

}  // namespace

extern "C" void kernel_launch(void* const* d_in, const int* in_sizes, int n_in,
                              void* d_out, int out_size, void* d_ws, size_t ws_size,
                              hipStream_t stream) {
  const float* x    = (const float*)d_in[0];
  const float* r    = (const float*)d_in[1];
  const float* n1w  = (const float*)d_in[2];
  const float* n1b  = (const float*)d_in[3];
  const float* c1w1 = (const float*)d_in[4];
  const float* c1b1 = (const float*)d_in[5];
  const float* c1w2 = (const float*)d_in[6];
  const float* c1b2 = (const float*)d_in[7];
  const float* n2w  = (const float*)d_in[8];
  const float* n2b  = (const float*)d_in[9];
  const float* c2w1 = (const float*)d_in[10];
  const float* c2b1 = (const float*)d_in[11];
  const float* c2w2 = (const float*)d_in[12];
  const float* c2b2 = (const float*)d_in[13];
  float* out = (float*)d_out;

  // workspace layout: Y (64 MiB) | Z (64 MiB) | stats (1 KiB)  -> needs 128 MiB + 1 KiB
  float* Yw    = (float*)d_ws;
  float* Zw    = Yw + (size_t)Bn * CHWn;
  float* stats = Zw + (size_t)Bn * CHWn;

  ShiftConsts sc;
  for (int s = 0; s < 9; s++) {
    const int sw = s / 3 - 1, sh = s % 3 - 1;
    const double ca = cos(sw * 0.006135923151542565);
    const double sa = sin(sw * 0.006135923151542565);
    const double ci = cos(sh * 0.008267349088394194);
    const double si = sin(sh * 0.008267349088394194);
    sc.m[s]      = (float)(ca * ci);
    sc.m[9 + s]  = (float)(ca * si);
    sc.m[18 + s] = (float)sa;
  }

  // ---- block 1 ----
  gn_stats_kernel<<<128, 256, 0, stream>>>(x, stats);
  dual_gemm_kernel<<<4096, 256, 0, stream>>>(x, stats, n1w, n1b, c1w1, c1b1, Yw, Zw);
  shift_max_kernel<<<2048, 256, 0, stream>>>(Yw, Zw, r, c1w1, c1w2, c1b2, x, 0, out, sc);
  // ---- block 2 (edge_conv1 result parked in d_out) ----
  gn_stats_kernel<<<128, 256, 0, stream>>>(out, stats);
  dual_gemm_kernel<<<4096, 256, 0, stream>>>(out, stats, n2w, n2b, c2w1, c2b1, Yw, Zw);
  shift_max_kernel<<<2048, 256, 0, stream>>>(Yw, Zw, r, c2w1, c2w2, c2b2, x, 1, out, sc);
}

// Round 2
// 462.528 us; speedup vs baseline: 4.1984x; 4.1984x over previous
//
#include <hip/hip_runtime.h>
#include <cmath>
#include <math.h>

namespace {

constexpr int Bn = 4;
constexpr int Cn = 64;
constexpr int Wn = 64;
constexpr int Hn = 1024;
constexpr int HWn = Wn * Hn;      // 65536
constexpr int CHWn = Cn * HWn;    // 4194304

struct ShiftConsts { float m[27]; };  // m0[9] | m1[9] | m2[9]

typedef float f32x4 __attribute__((ext_vector_type(4)));
typedef short bf16x8 __attribute__((ext_vector_type(8)));
union Frag { uint4 u; bf16x8 s; };

__device__ inline unsigned bf16rne(float f) {
  unsigned u = __float_as_uint(f);
  return (u + 0x7FFFu + ((u >> 16) & 1u)) >> 16;
}
__device__ inline unsigned packbf(float a, float b) {
  return bf16rne(a) | (bf16rne(b) << 16);
}
__device__ inline float bflo(unsigned d) { return __uint_as_float(d << 16); }
__device__ inline float bfhi(unsigned d) { return __uint_as_float(d & 0xFFFF0000u); }

// ---------------- GroupNorm stats, stage 1: partial sums (atomic) ----------------
__global__ __launch_bounds__(256) void gn_partial_kernel(
    const float* __restrict__ x, float* __restrict__ partial) {
  const int bg = blockIdx.x >> 4, part = blockIdx.x & 15;
  const float4* base = (const float4*)(x + (size_t)bg * 2 * HWn) + part * 2048;
  float s = 0.f, s2 = 0.f;
  for (int i = threadIdx.x; i < 2048; i += 256) {
    const float4 v = base[i];
    s += v.x + v.y + v.z + v.w;
    s2 += v.x * v.x + v.y * v.y + v.z * v.z + v.w * v.w;
  }
  #pragma unroll
  for (int off = 32; off > 0; off >>= 1) {
    s  += __shfl_down(s, off, 64);
    s2 += __shfl_down(s2, off, 64);
  }
  __shared__ float red[8];
  const int wid = threadIdx.x >> 6, lid = threadIdx.x & 63;
  if (lid == 0) { red[wid * 2] = s; red[wid * 2 + 1] = s2; }
  __syncthreads();
  if (threadIdx.x == 0) {
    float ts = red[0] + red[2] + red[4] + red[6];
    float t2 = red[1] + red[3] + red[5] + red[7];
    atomicAdd(&partial[bg * 2], ts);
    atomicAdd(&partial[bg * 2 + 1], t2);
  }
}

// ---------------- GroupNorm stats, stage 2: finalize ----------------
__global__ void gn_final_kernel(const float* __restrict__ partial,
                                float* __restrict__ stats) {
  const int i = threadIdx.x;
  if (i < 128) {
    const float inv = 1.0f / (2.0f * HWn);
    const float mean = partial[2 * i] * inv;
    const float var = partial[2 * i + 1] * inv - mean * mean;
    stats[2 * i] = mean;
    stats[2 * i + 1] = rsqrtf(var + 1e-6f);
  }
}

// ------- Dual GEMM (MFMA): Y = W_a @ relu(gn(x)), Z = W_b @ relu(gn(x)) + b1 -------
// Output layout: NHWC bf16: Y[((b*64+w)*1024+h)*64 + k]
__global__ __launch_bounds__(256, 2) void dual_gemm_kernel(
    const float* __restrict__ x, const float* __restrict__ stats,
    const float* __restrict__ gw, const float* __restrict__ gb,
    const float* __restrict__ w1, const float* __restrict__ b1,
    ushort* __restrict__ Y, ushort* __restrict__ Z) {
  __shared__ float2 scsh[64];
  __shared__ float bias[64];
  __shared__ __align__(16) ushort dsY[64 * 72];
  __shared__ __align__(16) ushort dsZ[64 * 72];
  const int blk = blockIdx.x;
  const int h0 = (blk & 15) * 64;
  const int w  = (blk >> 4) & 63;
  const int b  = blk >> 10;
  const int t  = threadIdx.x;
  const int lane = t & 63, wv = t >> 6;
  const int n = lane & 15, q = lane >> 4;

  if (t < 64) {
    const int g = t >> 1;
    const float mean = stats[(b * 32 + g) * 2];
    const float rstd = stats[(b * 32 + g) * 2 + 1];
    const float sc = rstd * gw[t];
    scsh[t] = make_float2(sc, gb[t] - mean * sc);
    bias[t] = b1[t];
  }
  __syncthreads();

  // B fragments (xn), built directly in registers. n = local j col.
  const int jg = h0 + wv * 16 + n;  // global h
  const float* xb = x + (size_t)b * CHWn + (size_t)w * Hn;
  Frag Bf[2];
  #pragma unroll
  for (int kh = 0; kh < 2; kh++) {
    unsigned d[4];
    #pragma unroll
    for (int p = 0; p < 4; p++) {
      const int c0 = kh * 32 + q * 8 + p * 2;
      const float2 s0 = scsh[c0], s1 = scsh[c0 + 1];
      const float v0 = fmaxf(xb[(size_t)c0 * HWn + jg] * s0.x + s0.y, 0.f);
      const float v1 = fmaxf(xb[(size_t)(c0 + 1) * HWn + jg] * s1.x + s1.y, 0.f);
      d[p] = packbf(v0, v1);
    }
    Bf[kh].u = make_uint4(d[0], d[1], d[2], d[3]);
  }

  f32x4 accY[4], accZ[4];
  #pragma unroll
  for (int os = 0; os < 4; os++) { accY[os] = (f32x4)0.f; accZ[os] = (f32x4)0.f; }

  #pragma unroll
  for (int os = 0; os < 4; os++) {
    const int o = os * 16 + n;  // A row m = lane&15
    #pragma unroll
    for (int kh = 0; kh < 2; kh++) {
      const int k = kh * 32 + q * 8;
      const float* wra = w1 + o * 131 + k;       // W_a
      const float* wrb = w1 + o * 131 + 64 + k;  // W_b
      Frag fa, fb;
      unsigned da[4], db[4];
      #pragma unroll
      for (int p = 0; p < 4; p++) {
        da[p] = packbf(wra[2 * p], wra[2 * p + 1]);
        db[p] = packbf(wrb[2 * p], wrb[2 * p + 1]);
      }
      fa.u = make_uint4(da[0], da[1], da[2], da[3]);
      fb.u = make_uint4(db[0], db[1], db[2], db[3]);
      accY[os] = __builtin_amdgcn_mfma_f32_16x16x32_bf16(fa.s, Bf[kh].s, accY[os], 0, 0, 0);
      accZ[os] = __builtin_amdgcn_mfma_f32_16x16x32_bf16(fb.s, Bf[kh].s, accZ[os], 0, 0, 0);
    }
  }

  // D -> LDS repack: ds[j][o] (stride 72), bf16 pairs along o.
  const int jl = wv * 16 + n;
  #pragma unroll
  for (int os = 0; os < 4; os++) {
    #pragma unroll
    for (int rp = 0; rp < 4; rp += 2) {
      const int o = os * 16 + q * 4 + rp;
      *(unsigned*)&dsY[jl * 72 + o] = packbf(accY[os][rp], accY[os][rp + 1]);
      *(unsigned*)&dsZ[jl * 72 + o] =
          packbf(accZ[os][rp] + bias[o], accZ[os][rp + 1] + bias[o + 1]);
    }
  }
  __syncthreads();

  // Coalesced NHWC store
  #pragma unroll
  for (int p = 0; p < 2; p++) {
    const int slot = t + 256 * p;
    const int j = slot >> 3, og = slot & 7;
    const size_t gidx = (((size_t)b * Wn + w) * Hn + h0 + j) * 64 + og * 8;
    *(uint4*)&Y[gidx] = *(const uint4*)&dsY[j * 72 + og * 8];
    *(uint4*)&Z[gidx] = *(const uint4*)&dsZ[j * 72 + og * 8];
  }
}

// ---- 9-shift fused MFMA: out = max_s( W2 @ relu(Y_s + Z + pe_s) ) + b2 (+ x) ----
__global__ __launch_bounds__(256, 2) void shift_max_kernel(
    const ushort* __restrict__ Y, const ushort* __restrict__ Z,
    const float* __restrict__ r, const float* __restrict__ w1,
    const float* __restrict__ w2, const float* __restrict__ b2,
    const float* __restrict__ xres, const int add_res,
    float* __restrict__ out, const ShiftConsts sc) {
  __shared__ __align__(16) ushort zs[64 * 72];   // [j][k]
  __shared__ __align__(16) ushort ys[66 * 72];   // [jj][k], jj = h0-1 .. h0+64
  __shared__ __align__(16) ushort h1s[64 * 72];  // [j][k]
  __shared__ float rsh[3][68];
  const int blk = blockIdx.x;
  const int h0 = (blk & 15) * 64;
  const int w  = (blk >> 4) & 63;
  const int b  = blk >> 10;
  const int t  = threadIdx.x;
  const int lane = t & 63, wv = t >> 6;
  const int n = lane & 15, q = lane >> 4;

  // w2 A-fragments, resident all kernel. w2 is [o][64] fp32, 256B-aligned rows.
  Frag A[8];  // [os][kh]
  #pragma unroll
  for (int os = 0; os < 4; os++) {
    const int o = os * 16 + n;
    #pragma unroll
    for (int kh = 0; kh < 2; kh++) {
      const float4 f0 = *(const float4*)&w2[o * 64 + kh * 32 + q * 8];
      const float4 f1 = *(const float4*)&w2[o * 64 + kh * 32 + q * 8 + 4];
      A[os * 2 + kh].u = make_uint4(packbf(f0.x, f0.y), packbf(f0.z, f0.w),
                                    packbf(f1.x, f1.y), packbf(f1.z, f1.w));
    }
  }

  // per-thread k-group for the build phase (fixed across slots)
  const int kg = t & 7, k0 = kg * 8;
  float pw0v[8], pw1v[8], pw2v[8];
  #pragma unroll
  for (int i = 0; i < 8; i++) {
    pw0v[i] = w1[(k0 + i) * 131 + 128];
    pw1v[i] = w1[(k0 + i) * 131 + 129];
    pw2v[i] = w1[(k0 + i) * 131 + 130];
  }

  // r halo
  for (int i = t; i < 3 * 66; i += 256) {
    const int wi = i / 66, jj = i - wi * 66;
    const int wsrc = (w + wi - 1 + 64) & 63;
    const int hsrc = (h0 + jj - 1 + 1024) & 1023;
    rsh[wi][jj] = r[(size_t)b * HWn + wsrc * Hn + hsrc];
  }
  // Z tile (shift-invariant)
  #pragma unroll
  for (int p = 0; p < 2; p++) {
    const int slot = t + 256 * p;
    const int j = slot >> 3, kg2 = slot & 7;
    *(uint4*)&zs[j * 72 + kg2 * 8] =
        *(const uint4*)&Z[(((size_t)b * Wn + w) * Hn + h0 + j) * 64 + kg2 * 8];
  }

  f32x4 om[4];
  #pragma unroll
  for (int os = 0; os < 4; os++) om[os] = (f32x4)(-INFINITY);

  const int jl = wv * 16 + n;  // this lane's B column (local j)

  for (int sw = -1; sw <= 1; sw++) {
    const int wsrc = (w - sw + 64) & 63;
    __syncthreads();  // ys readers from previous sw done; zs/rsh ready on first pass
    #pragma unroll
    for (int p = 0; p < 3; p++) {
      const int slot = t + 256 * p;
      if (slot < 66 * 8) {
        const int jj = slot >> 3, kg2 = slot & 7;
        const int hsrc = (h0 + jj - 1 + 1024) & 1023;
        *(uint4*)&ys[jj * 72 + kg2 * 8] =
            *(const uint4*)&Y[(((size_t)b * Wn + wsrc) * Hn + hsrc) * 64 + kg2 * 8];
      }
    }
    __syncthreads();
    for (int sh = -1; sh <= 1; sh++) {
      const int s = (sw + 1) * 3 + (sh + 1);
      const float m0 = sc.m[s], m1 = sc.m[9 + s], m2 = sc.m[18 + s];
      float vs[8];
      #pragma unroll
      for (int i = 0; i < 8; i++)
        vs[i] = m0 * pw0v[i] + m1 * pw1v[i] + m2 * pw2v[i];
      // build h1 = relu(y + z + rsv*vs - rc*pw0) -> bf16 LDS [j][k]
      #pragma unroll
      for (int p = 0; p < 2; p++) {
        const int slot = t + 256 * p;
        const int j = slot >> 3;  // kg == t&7 for both passes
        const uint4 y4 = *(const uint4*)&ys[(j - sh + 1) * 72 + k0];
        const uint4 z4 = *(const uint4*)&zs[j * 72 + k0];
        const float rsv = rsh[1 - sw][j - sh + 1];
        const float rc  = rsh[1][j + 1];
        const unsigned yw[4] = {y4.x, y4.y, y4.z, y4.w};
        const unsigned zw[4] = {z4.x, z4.y, z4.z, z4.w};
        unsigned hw[4];
        #pragma unroll
        for (int p2 = 0; p2 < 4; p2++) {
          const float h0f = bflo(yw[p2]) + bflo(zw[p2]) + rsv * vs[2 * p2] - rc * pw0v[2 * p2];
          const float h1f = bfhi(yw[p2]) + bfhi(zw[p2]) + rsv * vs[2 * p2 + 1] - rc * pw0v[2 * p2 + 1];
          hw[p2] = packbf(fmaxf(h0f, 0.f), fmaxf(h1f, 0.f));
        }
        *(uint4*)&h1s[j * 72 + k0] = make_uint4(hw[0], hw[1], hw[2], hw[3]);
      }
      __syncthreads();
      // GEMM: D = w2 @ h1, fmax into om
      Frag Bf0, Bf1;
      Bf0.u = *(const uint4*)&h1s[jl * 72 + q * 8];
      Bf1.u = *(const uint4*)&h1s[jl * 72 + 32 + q * 8];
      #pragma unroll
      for (int os = 0; os < 4; os++) {
        f32x4 acc = (f32x4)0.f;
        acc = __builtin_amdgcn_mfma_f32_16x16x32_bf16(A[os * 2].s, Bf0.s, acc, 0, 0, 0);
        acc = __builtin_amdgcn_mfma_f32_16x16x32_bf16(A[os * 2 + 1].s, Bf1.s, acc, 0, 0, 0);
        #pragma unroll
        for (int e = 0; e < 4; e++) om[os][e] = fmaxf(om[os][e], acc[e]);
      }
      __syncthreads();
    }
  }

  // epilogue: D layout col=lane&15 (j), row=q*4+e (o)
  const int jgl = h0 + jl;
  #pragma unroll
  for (int os = 0; os < 4; os++) {
    #pragma unroll
    for (int e = 0; e < 4; e++) {
      const int o = os * 16 + q * 4 + e;
      const size_t idx = ((size_t)b * Cn + o) * HWn + (size_t)w * Hn + jgl;
      float v = om[os][e] + b2[o];
      if (add_res) v += xres[idx];
      out[idx] = v;
    }
  }
}

}  // namespace

extern "C" void kernel_launch(void* const* d_in, const int* in_sizes, int n_in,
                              void* d_out, int out_size, void* d_ws, size_t ws_size,
                              hipStream_t stream) {
  const float* x    = (const float*)d_in[0];
  const float* r    = (const float*)d_in[1];
  const float* n1w  = (const float*)d_in[2];
  const float* n1b  = (const float*)d_in[3];
  const float* c1w1 = (const float*)d_in[4];
  const float* c1b1 = (const float*)d_in[5];
  const float* c1w2 = (const float*)d_in[6];
  const float* c1b2 = (const float*)d_in[7];
  const float* n2w  = (const float*)d_in[8];
  const float* n2b  = (const float*)d_in[9];
  const float* c2w1 = (const float*)d_in[10];
  const float* c2b1 = (const float*)d_in[11];
  const float* c2w2 = (const float*)d_in[12];
  const float* c2b2 = (const float*)d_in[13];
  float* out = (float*)d_out;

  // ws: [partial 256f][stats 256f][pad to 4096B][Y bf16 32MiB][Z bf16 32MiB]
  float* partial = (float*)d_ws;
  float* statsf  = partial + 256;
  ushort* Ybf = (ushort*)((char*)d_ws + 4096);
  ushort* Zbf = Ybf + (size_t)Bn * Wn * Hn * 64;

  ShiftConsts sc;
  for (int s = 0; s < 9; s++) {
    const int sw = s / 3 - 1, sh = s % 3 - 1;
    const double ca = cos(sw * 0.006135923151542565);
    const double sa = sin(sw * 0.006135923151542565);
    const double ci = cos(sh * 0.008267349088394194);
    const double si = sin(sh * 0.008267349088394194);
    sc.m[s]      = (float)(ca * ci);
    sc.m[9 + s]  = (float)(ca * si);
    sc.m[18 + s] = (float)sa;
  }

  // ---- block 1 ----
  hipMemsetAsync(partial, 0, 256 * sizeof(float), stream);
  gn_partial_kernel<<<2048, 256, 0, stream>>>(x, partial);
  gn_final_kernel<<<1, 128, 0, stream>>>(partial, statsf);
  dual_gemm_kernel<<<4096, 256, 0, stream>>>(x, statsf, n1w, n1b, c1w1, c1b1, Ybf, Zbf);
  shift_max_kernel<<<4096, 256, 0, stream>>>(Ybf, Zbf, r, c1w1, c1w2, c1b2, x, 0, out, sc);
  // ---- block 2 (edge_conv1 result parked in d_out) ----
  hipMemsetAsync(partial, 0, 256 * sizeof(float), stream);
  gn_partial_kernel<<<2048, 256, 0, stream>>>(out, partial);
  gn_final_kernel<<<1, 128, 0, stream>>>(partial, statsf);
  dual_gemm_kernel<<<4096, 256, 0, stream>>>(out, statsf, n2w, n2b, c2w1, c2b1, Ybf, Zbf);
  shift_max_kernel<<<4096, 256, 0, stream>>>(Ybf, Zbf, r, c2w1, c2w2, c2b2, x, 1, out, sc);
}